// Round 3
// baseline (292.025 us; speedup 1.0000x reference)
//
#include <hip/hip_runtime.h>

// B,T,E,H from reference setup_inputs()
#define B_ 16
#define T_ 2048
#define E_ 1024
#define H_ 128

typedef short bf16x8 __attribute__((ext_vector_type(8)));
typedef float f32x4 __attribute__((ext_vector_type(4)));
typedef unsigned short u16x4 __attribute__((ext_vector_type(4)));

static __device__ __forceinline__ unsigned short f2bf(float f) {
    unsigned int u = __float_as_uint(f);
    u += 0x7FFFu + ((u >> 16) & 1u);   // round-to-nearest-even
    return (unsigned short)(u >> 16);
}
static __device__ __forceinline__ unsigned int pk2(unsigned short a, unsigned short b) {
    return (unsigned int)a | ((unsigned int)b << 16);
}
static __device__ __forceinline__ bf16x8 frag(uint4 v) {
    return __builtin_bit_cast(bf16x8, v);
}
// async global->LDS, 16 B per lane; LDS dest = wave-uniform base + lane*16
static __device__ __forceinline__ void gl16(const unsigned short* g, unsigned short* l) {
    __builtin_amdgcn_global_load_lds(
        (const __attribute__((address_space(1))) void*)g,
        (__attribute__((address_space(3))) void*)l, 16, 0, 0);
}

// ---------------------------------------------------------------------------
// Kernel A: W fp32->bf16 transposed to wt[n][k] (n = q|k|v rows, 0..383).
// ---------------------------------------------------------------------------
__global__ __launch_bounds__(256) void cvtw_kernel(
    const float* __restrict__ w0, const float* __restrict__ w1,
    const float* __restrict__ w2, unsigned short* __restrict__ wt)
{
    int g   = blockIdx.x * 256 + threadIdx.x;   // 0..49151
    int arr = g >> 14;
    int rem = g & 16383;
    int h   = rem >> 7;
    int e0  = (rem & 127) * 8;
    const float* src = (arr == 0) ? w0 : (arr == 1) ? w1 : w2;
    unsigned short b[8];
#pragma unroll
    for (int i = 0; i < 8; i++) b[i] = f2bf(src[(size_t)(e0 + i) * H_ + h]);
    uint4 o;
    o.x = pk2(b[0], b[1]); o.y = pk2(b[2], b[3]);
    o.z = pk2(b[4], b[5]); o.w = pk2(b[6], b[7]);
    *(uint4*)&wt[(size_t)(arr * 128 + h) * E_ + e0] = o;
}

// ---------------------------------------------------------------------------
// Kernel 1: FUSED QKV projection, 128x384 tile, 512 thr (8 waves 2x4,
// acc[4][6]). x read fp32 ONCE. ALL staging reg-staged (A converts to bf16
// in-reg; B is bf16 from wt). T14 pipeline with RAW s_barrier (no vmcnt
// drain): depth-3 global prefetch (load tile kb+3 in segment kb), publish
// tile kb+1 right after the barrier; only lgkmcnt(0) is waited at the
// barrier, so global loads stay in flight across it and the compiler emits
// counted vmcnt waits only before the ds_write that consumes them
// (~2-iteration latency window). LDS 64 KB, 1 block/CU, 2 waves/SIMD.
// ---------------------------------------------------------------------------
__global__ __launch_bounds__(512, 2) void proj_kernel(
    const float* __restrict__ x,
    const unsigned short* __restrict__ wt,
    unsigned short* __restrict__ q_ws,
    unsigned short* __restrict__ kp_ws,
    unsigned short* __restrict__ vt_ws)
{
    const int m0 = blockIdx.x * 128;
    __shared__ __align__(16) unsigned short As[2][128 * 32];   // 8 KB each
    __shared__ __align__(16) unsigned short Bs[2][384 * 32];   // 24 KB each

    const int tid  = threadIdx.x;
    const int lane = tid & 63;
    const int w    = tid >> 6;          // 0..7
    const int quad = lane >> 4;
    const int lm   = lane & 15;
    const int wr   = (w >> 2) * 64;     // 0,64
    const int wc   = (w & 3) * 96;      // 0,96,192,288

    // staging indices: identical for A and B chunks
    const int srow = tid >> 2;          // 0..127
    const int scol = (tid & 3) * 8;     // 0,8,16,24
    const float* gx = x + (size_t)(m0 + srow) * E_ + scol;
    const unsigned short* gw = wt + (size_t)srow * E_ + scol;   // +i*128 rows

    const f32x4 z4 = {0.f, 0.f, 0.f, 0.f};
    f32x4 acc[4][6];
#pragma unroll
    for (int i = 0; i < 4; i++)
#pragma unroll
        for (int j = 0; j < 6; j++) acc[i][j] = z4;

    struct StA { float4 a0, a1; };
    struct StB { uint4 b0, b1, b2; };

    auto ldA = [&](int kb) {
        StA r;
        const float* g = gx + kb * 32;
        r.a0 = *(const float4*)g;
        r.a1 = *(const float4*)(g + 4);
        return r;
    };
    auto ldB = [&](int kb) {
        StB r;
        const unsigned short* g = gw + kb * 32;
        r.b0 = *(const uint4*)g;
        r.b1 = *(const uint4*)(g + (size_t)128 * E_);
        r.b2 = *(const uint4*)(g + (size_t)256 * E_);
        return r;
    };
    auto stAB = [&](const StA& a, const StB& b, int buf) {
        uint4 o;
        o.x = pk2(f2bf(a.a0.x), f2bf(a.a0.y));
        o.y = pk2(f2bf(a.a0.z), f2bf(a.a0.w));
        o.z = pk2(f2bf(a.a1.x), f2bf(a.a1.y));
        o.w = pk2(f2bf(a.a1.z), f2bf(a.a1.w));
        *(uint4*)&As[buf][srow * 32 + scol]        = o;
        *(uint4*)&Bs[buf][srow * 32 + scol]        = b.b0;
        *(uint4*)&Bs[buf][srow * 32 + scol + 4096] = b.b1;
        *(uint4*)&Bs[buf][srow * 32 + scol + 8192] = b.b2;
    };

    // prologue: tile 0 staged; tiles 1,2 in registers (depth-3 pipeline)
    {
        StA a0v = ldA(0); StB b0v = ldB(0);
        stAB(a0v, b0v, 0);
    }
    StA a1v = ldA(1); StB b1v = ldB(1);
    StA a2v = ldA(2); StB b2v = ldB(2);

    for (int kb = 0; kb < 32; kb++) {
        const int cb = kb & 1;
        // raw barrier: drain LDS ops only; global prefetches stay in flight
        asm volatile("s_waitcnt lgkmcnt(0)" ::: "memory");
        __builtin_amdgcn_sched_barrier(0);
        __builtin_amdgcn_s_barrier();
        __builtin_amdgcn_sched_barrier(0);

        // prefetch tile kb+3 (clamped duplicates at tail — dead, harmless)
        const int kn = (kb + 3 < 32) ? kb + 3 : 31;
        StA an = ldA(kn); StB bn = ldB(kn);

        // publish tile kb+1 into the other buffer (regs loaded 2 segs ago)
        if (kb + 1 < 32) stAB(a1v, b1v, cb ^ 1);

        // compute tile kb
        bf16x8 a[4], b[6];
#pragma unroll
        for (int am = 0; am < 4; am++)
            a[am] = frag(*(const uint4*)&As[cb][(wr + am * 16 + lm) * 32 + quad * 8]);
#pragma unroll
        for (int bnn = 0; bnn < 6; bnn++)
            b[bnn] = frag(*(const uint4*)&Bs[cb][(wc + bnn * 16 + lm) * 32 + quad * 8]);
#pragma unroll
        for (int am = 0; am < 4; am++)
#pragma unroll
            for (int bnn = 0; bnn < 6; bnn++)
                acc[am][bnn] = __builtin_amdgcn_mfma_f32_16x16x32_bf16(
                    a[am], b[bnn], acc[am][bnn], 0, 0, 0);

        a1v = a2v; b1v = b2v;
        a2v = an;  b2v = bn;
    }

    // epilogue: route each 16-col fragment to q / kp / vt by column block
#pragma unroll
    for (int am = 0; am < 4; am++)
#pragma unroll
        for (int bn = 0; bn < 6; bn++) {
            const int gcol  = wc + bn * 16 + lm;      // 0..383
            const int sel   = gcol >> 7;              // 0=q 1=k 2=v (wave-uniform)
            const int c     = gcol & 127;
            const int rbase = m0 + wr + am * 16 + quad * 4;
            const int bb    = rbase >> 11;
            const int t     = rbase & 2047;
            if (sel == 0) {
#pragma unroll
                for (int r = 0; r < 4; r++)
                    q_ws[(size_t)(rbase + r) * H_ + c] = f2bf(acc[am][bn][r]);
            } else if (sel == 1) {
#pragma unroll
                for (int r = 0; r < 4; r++) {
                    int tt = t + r;
                    kp_ws[(size_t)(bb * 64 + (tt >> 5)) * 4096 +
                          (c >> 5) * 1024 + (tt & 31) * 32 + (c & 31)] =
                        f2bf(acc[am][bn][r]);
                }
            } else {
                u16x4 pv;
#pragma unroll
                for (int r = 0; r < 4; r++) pv[r] = f2bf(acc[am][bn][r]);
                *(u16x4*)&vt_ws[((size_t)(bb * 64 + (t >> 5)) * 128 + c) * 32 + (t & 31)] = pv;
            }
        }
}

// ---------------------------------------------------------------------------
// Kernel 2: causal flash attention, grid 512 (2 blocks/CU). NEW: triple-
// buffered K/V with counted vmcnt — per wave exactly 4 gl16 per segment, so
// "s_waitcnt vmcnt(4)" at iter kt leaves only S(kt+1)'s 4 loads outstanding
// => S(kt) complete; raw s_barrier then publishes. Each tile's loads get ~2
// iterations of latency window instead of a full drain every iteration.
// Tail re-stages a duplicate tile into the dead buffer to keep the count
// invariant. LDS 53 KB/block -> 2 blocks/CU. T5 setprio kept.
// ---------------------------------------------------------------------------
__global__ __launch_bounds__(256, 2) void attn_kernel(
    const unsigned short* __restrict__ q_ws,
    const unsigned short* __restrict__ kp_ws,
    const unsigned short* __restrict__ vt_ws,
    float* __restrict__ out)
{
    __shared__ __align__(16) unsigned short Ks[3][4096];   // [h4][row32][32]
    __shared__ __align__(16) unsigned short Vs[3][4096];   // [col128][32]
    __shared__ __align__(16) unsigned short Ps[4][16][40];

    const int bid   = blockIdx.x;
    const int batch = bid & 15;
    const int p     = (bid >> 4) & 15;
    const int tau   = (bid >> 8) ? (31 - p) : p;
    const int nkt   = 2 * tau + 2;

    const int tid  = threadIdx.x;
    const int lane = tid & 63;
    const int ww   = tid >> 6;
    const int quad = lane >> 4;
    const int lm   = lane & 15;
    const float scale = 0.08838834764831845f;  // 1/sqrt(128)

    bf16x8 ones;
#pragma unroll
    for (int i = 0; i < 8; i++) ones[i] = (short)0x3F80;
    const f32x4 z4 = {0.f, 0.f, 0.f, 0.f};

    const size_t bq = (size_t)batch * T_ * H_;
    const int so = ww * 1024 + lane * 8;       // this wave's staging quarter
    const unsigned short* Kt = kp_ws + (size_t)(batch * 64) * 4096 + so;
    const unsigned short* Vt = vt_ws + (size_t)(batch * 64) * 4096 + so;

    auto stage = [&](int t, int b) {           // exactly 4 gl16 per wave
        const unsigned short* kg = Kt + (size_t)t * 4096;
        const unsigned short* vg = Vt + (size_t)t * 4096;
        gl16(kg,       &Ks[b][ww * 1024]);
        gl16(kg + 512, &Ks[b][ww * 1024 + 512]);
        gl16(vg,       &Vs[b][ww * 1024]);
        gl16(vg + 512, &Vs[b][ww * 1024 + 512]);
    };

    // Q B-frags for this wave's 16 q-rows
    bf16x8 qf[4];
#pragma unroll
    for (int h = 0; h < 4; h++)
        qf[h] = frag(*(const uint4*)(q_ws + bq +
                 (size_t)(tau * 64 + ww * 16 + lm) * H_ + h * 32 + quad * 8));

    f32x4 o[9];
#pragma unroll
    for (int f = 0; f < 9; f++) o[f] = z4;

    // prologue: tiles 0 and 1 in flight
    stage(0, 0);
    stage(1, 1);

    for (int kt = 0; kt < nkt; kt++) {
        const int cb = kt % 3;
        // counted wait: <=4 outstanding => S(kt) landed; then publish
        asm volatile("s_waitcnt vmcnt(4) lgkmcnt(0)" ::: "memory");
        __builtin_amdgcn_sched_barrier(0);
        __builtin_amdgcn_s_barrier();
        __builtin_amdgcn_sched_barrier(0);

        // issue tile kt+2 (clamped duplicate at tail keeps count invariant;
        // its target buffer (kt+2)%3 is never read again in that case)
        int ks = kt + 2; if (ks > nkt - 1) ks = nkt - 1;
        stage(ks, (kt + 2) % 3);

        // S^T = K.Q^T: row = quad*4+r (kv), col = lm (q)
        f32x4 st0 = z4, st1 = z4;
        __builtin_amdgcn_s_setprio(1);
#pragma unroll
        for (int h = 0; h < 4; h++) {
            bf16x8 kf0 = frag(*(const uint4*)&Ks[cb][(h * 32 + lm) * 32 + quad * 8]);
            bf16x8 kf1 = frag(*(const uint4*)&Ks[cb][(h * 32 + 16 + lm) * 32 + quad * 8]);
            st0 = __builtin_amdgcn_mfma_f32_16x16x32_bf16(kf0, qf[h], st0, 0, 0, 0);
            st1 = __builtin_amdgcn_mfma_f32_16x16x32_bf16(kf1, qf[h], st1, 0, 0, 0);
        }
        __builtin_amdgcn_s_setprio(0);

        // mask + exp -> P in wave-private LDS (A layout [q][kv])
        const int qg = tau * 64 + ww * 16 + lm;
        const int k0 = kt * 32;
        u16x4 pa, pb;
#pragma unroll
        for (int r = 0; r < 4; r++) {
            int kv0 = k0 + quad * 4 + r;
            float e0 = __expf(st0[r] * scale);
            float e1 = __expf(st1[r] * scale);
            pa[r] = (kv0      <= qg) ? f2bf(e0) : (unsigned short)0;
            pb[r] = (kv0 + 16 <= qg) ? f2bf(e1) : (unsigned short)0;
        }
        *(u16x4*)&Ps[ww][lm][quad * 4]      = pa;
        *(u16x4*)&Ps[ww][lm][16 + quad * 4] = pb;
        bf16x8 pf = frag(*(const uint4*)&Ps[ww][lm][quad * 8]);

        // O += P.V ; l via all-ones B-frag in o[8]
        __builtin_amdgcn_s_setprio(1);
#pragma unroll
        for (int f = 0; f < 8; f++) {
            bf16x8 vfr = frag(*(const uint4*)&Vs[cb][(f * 16 + lm) * 32 + quad * 8]);
            o[f] = __builtin_amdgcn_mfma_f32_16x16x32_bf16(pf, vfr, o[f], 0, 0, 0);
        }
        o[8] = __builtin_amdgcn_mfma_f32_16x16x32_bf16(pf, ones, o[8], 0, 0, 0);
        __builtin_amdgcn_s_setprio(0);
    }

    // epilogue: divide by l, store fp32
    float* op = out + bq + (size_t)(tau * 64 + ww * 16) * H_;
#pragma unroll
    for (int r = 0; r < 4; r++) {
        float inv = 1.f / o[8][r];
#pragma unroll
        for (int f = 0; f < 8; f++)
            op[(size_t)(quad * 4 + r) * H_ + f * 16 + lm] = o[f][r] * inv;
    }
}

// ---------------------------------------------------------------------------
extern "C" void kernel_launch(void* const* d_in, const int* in_sizes, int n_in,
                              void* d_out, int out_size, void* d_ws, size_t ws_size,
                              hipStream_t stream)
{
    // setup_inputs() order: x, Wk, Wq, Wv
    const float* x  = (const float*)d_in[0];
    const float* Wk = (const float*)d_in[1];
    const float* Wq = (const float*)d_in[2];
    const float* Wv = (const float*)d_in[3];
    float* out = (float*)d_out;

    const size_t MH = (size_t)B_ * T_ * H_;        // 4,194,304
    unsigned short* q_ws  = (unsigned short*)d_ws;
    unsigned short* kp_ws = q_ws + MH;             // packed [b][kt][h][row][32]
    unsigned short* vt_ws = kp_ws + MH;            // packed [b][kt][col][32]
    unsigned short* wt    = vt_ws + MH;            // [384][1024] bf16

    cvtw_kernel<<<dim3(192), dim3(256), 0, stream>>>(Wq, Wk, Wv, wt);
    proj_kernel<<<dim3(256), dim3(512), 0, stream>>>(x, wt, q_ws, kp_ws, vt_ws);
    attn_kernel<<<dim3(512), dim3(256), 0, stream>>>(q_ws, kp_ws, vt_ws, out);
}

// Round 4
// 283.671 us; speedup vs baseline: 1.0295x; 1.0295x over previous
//
#include <hip/hip_runtime.h>

// B,T,E,H from reference setup_inputs()
#define B_ 16
#define T_ 2048
#define E_ 1024
#define H_ 128

typedef short bf16x8 __attribute__((ext_vector_type(8)));
typedef float f32x4 __attribute__((ext_vector_type(4)));
typedef unsigned short u16x4 __attribute__((ext_vector_type(4)));

static __device__ __forceinline__ unsigned short f2bf(float f) {
    unsigned int u = __float_as_uint(f);
    u += 0x7FFFu + ((u >> 16) & 1u);   // round-to-nearest-even
    return (unsigned short)(u >> 16);
}
static __device__ __forceinline__ unsigned int pk2(unsigned short a, unsigned short b) {
    return (unsigned int)a | ((unsigned int)b << 16);
}
static __device__ __forceinline__ bf16x8 frag(uint4 v) {
    return __builtin_bit_cast(bf16x8, v);
}
// async global->LDS, 16 B per lane; LDS dest = wave-uniform base + lane*16
static __device__ __forceinline__ void gl16(const unsigned short* g, unsigned short* l) {
    __builtin_amdgcn_global_load_lds(
        (const __attribute__((address_space(1))) void*)g,
        (__attribute__((address_space(3))) void*)l, 16, 0, 0);
}

// ---------------------------------------------------------------------------
// Kernel A: W fp32->bf16 transposed to wt[n][k] (n = q|k|v rows, 0..383).
// ---------------------------------------------------------------------------
__global__ __launch_bounds__(256) void cvtw_kernel(
    const float* __restrict__ w0, const float* __restrict__ w1,
    const float* __restrict__ w2, unsigned short* __restrict__ wt)
{
    int g   = blockIdx.x * 256 + threadIdx.x;   // 0..49151
    int arr = g >> 14;
    int rem = g & 16383;
    int h   = rem >> 7;
    int e0  = (rem & 127) * 8;
    const float* src = (arr == 0) ? w0 : (arr == 1) ? w1 : w2;
    unsigned short b[8];
#pragma unroll
    for (int i = 0; i < 8; i++) b[i] = f2bf(src[(size_t)(e0 + i) * H_ + h]);
    uint4 o;
    o.x = pk2(b[0], b[1]); o.y = pk2(b[2], b[3]);
    o.z = pk2(b[4], b[5]); o.w = pk2(b[6], b[7]);
    *(uint4*)&wt[(size_t)(arr * 128 + h) * E_ + e0] = o;
}

// ---------------------------------------------------------------------------
// Kernel 1: FUSED QKV projection, 64x384 tile, 512 thr (8 waves, wave tile
// 64x48, acc[4][3]). x read fp32 ONCE. Staging = r1-proven structure:
// B via global_load_lds (double-buffered, 3 gl16/thread), A reg-staged
// fp32->bf16 (1 float4/thread, published 1 iter later), ONE __syncthreads
// per K-step. Halved tile -> grid 512 = 2 blocks/CU (LDS 56 KB, 112 KB/CU),
// 4 waves/SIMD: while one block drains vmcnt(0) at its barrier, the other
// computes (m114 overlap) — this is the fix for r3's all-pipes-idle 11%
// MfmaUtil at 1 block/CU.
// ---------------------------------------------------------------------------
__global__ __launch_bounds__(512, 4) void proj_kernel(
    const float* __restrict__ x,
    const unsigned short* __restrict__ wt,
    unsigned short* __restrict__ q_ws,
    unsigned short* __restrict__ kp_ws,
    unsigned short* __restrict__ vt_ws)
{
    const int m0 = blockIdx.x * 64;
    __shared__ __align__(16) unsigned short As[2][64 * 32];    // 4 KB each
    __shared__ __align__(16) unsigned short Bs[2][384 * 32];   // 24 KB each

    const int tid  = threadIdx.x;
    const int lane = tid & 63;
    const int w    = tid >> 6;          // 0..7
    const int quad = lane >> 4;
    const int lm   = lane & 15;
    const int wc   = w * 48;            // wave column base (0..336)

    // A staging: 512 thr x 4 elems = 64x32
    const int arow = tid >> 3;          // 0..63
    const int acol = (tid & 7) * 4;     // 0,4,..,28
    const float* gx = x + (size_t)(m0 + arow) * E_ + acol;

    // B staging (gl16): 512 thr x 8 elems x 3 chunks = 384x32
    const int brow = tid >> 2;          // 0..127
    const int bcol = (tid & 3) * 8;     // 0,8,16,24
    const unsigned short* gw = wt + (size_t)brow * E_ + bcol;

    const f32x4 z4 = {0.f, 0.f, 0.f, 0.f};
    f32x4 acc[4][3];
#pragma unroll
    for (int i = 0; i < 4; i++)
#pragma unroll
        for (int j = 0; j < 3; j++) acc[i][j] = z4;

    auto stageB = [&](int kb, int buf) {
        const unsigned short* g = gw + kb * 32;
        unsigned short* l = &Bs[buf][tid * 8];
        gl16(g,                    l);
        gl16(g + (size_t)128 * E_, l + 4096);
        gl16(g + (size_t)256 * E_, l + 8192);
    };
    auto writeA = [&](float4 v, int buf) {
        u16x4 o;
        o[0] = f2bf(v.x); o[1] = f2bf(v.y);
        o[2] = f2bf(v.z); o[3] = f2bf(v.w);
        *(u16x4*)&As[buf][arow * 32 + acol] = o;
    };

    // prologue: tile 0 staged; tile 1's A in registers
    float4 a = *(const float4*)gx;          // kb=0 data
    stageB(0, 0);
    writeA(a, 0);
    a = *(const float4*)(gx + 32);          // kb=1 data

    for (int kb = 0; kb < 32; kb++) {
        const int cb = kb & 1;
        __syncthreads();   // buf[cb] published (gl16 + ds_write drained)

        // A register prefetch for kb+2 (spans the whole iteration)
        const int kb2 = (kb + 2 < 32) ? kb + 2 : 31;
        float4 n = *(const float4*)(gx + kb2 * 32);
        if (kb + 1 < 32) {
            stageB(kb + 1, cb ^ 1);        // async into other buffer
            writeA(a, cb ^ 1);             // regs loaded last iteration
        }

        bf16x8 af[4], bf[3];
#pragma unroll
        for (int am = 0; am < 4; am++)
            af[am] = frag(*(const uint4*)&As[cb][(am * 16 + lm) * 32 + quad * 8]);
#pragma unroll
        for (int bn = 0; bn < 3; bn++)
            bf[bn] = frag(*(const uint4*)&Bs[cb][(wc + bn * 16 + lm) * 32 + quad * 8]);
#pragma unroll
        for (int am = 0; am < 4; am++)
#pragma unroll
            for (int bn = 0; bn < 3; bn++)
                acc[am][bn] = __builtin_amdgcn_mfma_f32_16x16x32_bf16(
                    af[am], bf[bn], acc[am][bn], 0, 0, 0);

        a = n;
    }

    // epilogue: route each 16-col fragment to q / kp / vt by column block
#pragma unroll
    for (int am = 0; am < 4; am++)
#pragma unroll
        for (int bn = 0; bn < 3; bn++) {
            const int gcol  = wc + bn * 16 + lm;      // 0..383
            const int sel   = gcol >> 7;              // 0=q 1=k 2=v (uniform/frag)
            const int c     = gcol & 127;
            const int rbase = m0 + am * 16 + quad * 4;
            const int bb    = rbase >> 11;
            const int t     = rbase & 2047;
            if (sel == 0) {
#pragma unroll
                for (int r = 0; r < 4; r++)
                    q_ws[(size_t)(rbase + r) * H_ + c] = f2bf(acc[am][bn][r]);
            } else if (sel == 1) {
#pragma unroll
                for (int r = 0; r < 4; r++) {
                    int tt = t + r;
                    kp_ws[(size_t)(bb * 64 + (tt >> 5)) * 4096 +
                          (c >> 5) * 1024 + (tt & 31) * 32 + (c & 31)] =
                        f2bf(acc[am][bn][r]);
                }
            } else {
                u16x4 pv;
#pragma unroll
                for (int r = 0; r < 4; r++) pv[r] = f2bf(acc[am][bn][r]);
                *(u16x4*)&vt_ws[((size_t)(bb * 64 + (t >> 5)) * 128 + c) * 32 + (t & 31)] = pv;
            }
        }
}

// ---------------------------------------------------------------------------
// Kernel 2: causal flash attention, grid 512 (2 blocks/CU), triple-buffered
// K/V with counted vmcnt (4 gl16/wave/segment; vmcnt(4) at iter kt leaves
// only S(kt+1) outstanding => S(kt) landed), raw s_barrier, T5 setprio.
// Tail re-stages a duplicate tile into the dead buffer to keep the count
// invariant. LDS 53 KB/block. Unchanged from r3 (passed, ~45 us).
// ---------------------------------------------------------------------------
__global__ __launch_bounds__(256, 2) void attn_kernel(
    const unsigned short* __restrict__ q_ws,
    const unsigned short* __restrict__ kp_ws,
    const unsigned short* __restrict__ vt_ws,
    float* __restrict__ out)
{
    __shared__ __align__(16) unsigned short Ks[3][4096];   // [h4][row32][32]
    __shared__ __align__(16) unsigned short Vs[3][4096];   // [col128][32]
    __shared__ __align__(16) unsigned short Ps[4][16][40];

    const int bid   = blockIdx.x;
    const int batch = bid & 15;
    const int p     = (bid >> 4) & 15;
    const int tau   = (bid >> 8) ? (31 - p) : p;
    const int nkt   = 2 * tau + 2;

    const int tid  = threadIdx.x;
    const int lane = tid & 63;
    const int ww   = tid >> 6;
    const int quad = lane >> 4;
    const int lm   = lane & 15;
    const float scale = 0.08838834764831845f;  // 1/sqrt(128)

    bf16x8 ones;
#pragma unroll
    for (int i = 0; i < 8; i++) ones[i] = (short)0x3F80;
    const f32x4 z4 = {0.f, 0.f, 0.f, 0.f};

    const size_t bq = (size_t)batch * T_ * H_;
    const int so = ww * 1024 + lane * 8;       // this wave's staging quarter
    const unsigned short* Kt = kp_ws + (size_t)(batch * 64) * 4096 + so;
    const unsigned short* Vt = vt_ws + (size_t)(batch * 64) * 4096 + so;

    auto stage = [&](int t, int b) {           // exactly 4 gl16 per wave
        const unsigned short* kg = Kt + (size_t)t * 4096;
        const unsigned short* vg = Vt + (size_t)t * 4096;
        gl16(kg,       &Ks[b][ww * 1024]);
        gl16(kg + 512, &Ks[b][ww * 1024 + 512]);
        gl16(vg,       &Vs[b][ww * 1024]);
        gl16(vg + 512, &Vs[b][ww * 1024 + 512]);
    };

    // Q B-frags for this wave's 16 q-rows
    bf16x8 qf[4];
#pragma unroll
    for (int h = 0; h < 4; h++)
        qf[h] = frag(*(const uint4*)(q_ws + bq +
                 (size_t)(tau * 64 + ww * 16 + lm) * H_ + h * 32 + quad * 8));

    f32x4 o[9];
#pragma unroll
    for (int f = 0; f < 9; f++) o[f] = z4;

    // prologue: tiles 0 and 1 in flight
    stage(0, 0);
    stage(1, 1);

    for (int kt = 0; kt < nkt; kt++) {
        const int cb = kt % 3;
        // counted wait: <=4 outstanding => S(kt) landed; then publish
        asm volatile("s_waitcnt vmcnt(4) lgkmcnt(0)" ::: "memory");
        __builtin_amdgcn_sched_barrier(0);
        __builtin_amdgcn_s_barrier();
        __builtin_amdgcn_sched_barrier(0);

        // issue tile kt+2 (clamped duplicate at tail keeps count invariant;
        // its target buffer (kt+2)%3 is never read again in that case)
        int ks = kt + 2; if (ks > nkt - 1) ks = nkt - 1;
        stage(ks, (kt + 2) % 3);

        // S^T = K.Q^T: row = quad*4+r (kv), col = lm (q)
        f32x4 st0 = z4, st1 = z4;
        __builtin_amdgcn_s_setprio(1);
#pragma unroll
        for (int h = 0; h < 4; h++) {
            bf16x8 kf0 = frag(*(const uint4*)&Ks[cb][(h * 32 + lm) * 32 + quad * 8]);
            bf16x8 kf1 = frag(*(const uint4*)&Ks[cb][(h * 32 + 16 + lm) * 32 + quad * 8]);
            st0 = __builtin_amdgcn_mfma_f32_16x16x32_bf16(kf0, qf[h], st0, 0, 0, 0);
            st1 = __builtin_amdgcn_mfma_f32_16x16x32_bf16(kf1, qf[h], st1, 0, 0, 0);
        }
        __builtin_amdgcn_s_setprio(0);

        // mask + exp -> P in wave-private LDS (A layout [q][kv])
        const int qg = tau * 64 + ww * 16 + lm;
        const int k0 = kt * 32;
        u16x4 pa, pb;
#pragma unroll
        for (int r = 0; r < 4; r++) {
            int kv0 = k0 + quad * 4 + r;
            float e0 = __expf(st0[r] * scale);
            float e1 = __expf(st1[r] * scale);
            pa[r] = (kv0      <= qg) ? f2bf(e0) : (unsigned short)0;
            pb[r] = (kv0 + 16 <= qg) ? f2bf(e1) : (unsigned short)0;
        }
        *(u16x4*)&Ps[ww][lm][quad * 4]      = pa;
        *(u16x4*)&Ps[ww][lm][16 + quad * 4] = pb;
        bf16x8 pf = frag(*(const uint4*)&Ps[ww][lm][quad * 8]);

        // O += P.V ; l via all-ones B-frag in o[8]
        __builtin_amdgcn_s_setprio(1);
#pragma unroll
        for (int f = 0; f < 8; f++) {
            bf16x8 vfr = frag(*(const uint4*)&Vs[cb][(f * 16 + lm) * 32 + quad * 8]);
            o[f] = __builtin_amdgcn_mfma_f32_16x16x32_bf16(pf, vfr, o[f], 0, 0, 0);
        }
        o[8] = __builtin_amdgcn_mfma_f32_16x16x32_bf16(pf, ones, o[8], 0, 0, 0);
        __builtin_amdgcn_s_setprio(0);
    }

    // epilogue: divide by l, store fp32
    float* op = out + bq + (size_t)(tau * 64 + ww * 16) * H_;
#pragma unroll
    for (int r = 0; r < 4; r++) {
        float inv = 1.f / o[8][r];
#pragma unroll
        for (int f = 0; f < 8; f++)
            op[(size_t)(quad * 4 + r) * H_ + f * 16 + lm] = o[f][r] * inv;
    }
}

// ---------------------------------------------------------------------------
extern "C" void kernel_launch(void* const* d_in, const int* in_sizes, int n_in,
                              void* d_out, int out_size, void* d_ws, size_t ws_size,
                              hipStream_t stream)
{
    // setup_inputs() order: x, Wk, Wq, Wv
    const float* x  = (const float*)d_in[0];
    const float* Wk = (const float*)d_in[1];
    const float* Wq = (const float*)d_in[2];
    const float* Wv = (const float*)d_in[3];
    float* out = (float*)d_out;

    const size_t MH = (size_t)B_ * T_ * H_;        // 4,194,304
    unsigned short* q_ws  = (unsigned short*)d_ws;
    unsigned short* kp_ws = q_ws + MH;             // packed [b][kt][h][row][32]
    unsigned short* vt_ws = kp_ws + MH;            // packed [b][kt][col][32]
    unsigned short* wt    = vt_ws + MH;            // [384][1024] bf16

    cvtw_kernel<<<dim3(192), dim3(256), 0, stream>>>(Wq, Wk, Wv, wt);
    proj_kernel<<<dim3(512), dim3(512), 0, stream>>>(x, wt, q_ws, kp_ws, vt_ws);
    attn_kernel<<<dim3(512), dim3(256), 0, stream>>>(q_ws, kp_ws, vt_ws, out);
}